// Round 5
// baseline (359.400 us; speedup 1.0000x reference)
//
#include <hip/hip_runtime.h>

#define TT 16384
#define HH 1024
#define EE 8

typedef __attribute__((ext_vector_type(8))) short short8;
typedef __attribute__((ext_vector_type(4))) float f32x4;

__device__ inline unsigned short f2bf(float f) {
    union { float f; unsigned int u; } v; v.f = f;
    unsigned int u = v.u;
    unsigned int r = (u + 0x7FFFu + ((u >> 16) & 1u)) >> 16; // RNE
    return (unsigned short)r;
}

// ---------------------------------------------------------------------------
// Transpose + convert expert_w [E][H][H] fp32 (h-major) -> Wt [E][d][h] bf16
// ---------------------------------------------------------------------------
__global__ __launch_bounds__(256) void transpose_w_kernel(
    const float* __restrict__ w, unsigned short* __restrict__ wt)
{
    __shared__ unsigned short tile[64][66];
    int bid = blockIdx.x;
    int e   = bid >> 8;
    int rem = bid & 255;
    int hb  = ((rem >> 4) & 15) * 64;
    int db  = (rem & 15) * 64;
    int tid = threadIdx.x;
    int c4  = (tid & 15) * 4;
    int r0  = tid >> 4;

    const float* we = w + (size_t)e * HH * HH;
    #pragma unroll
    for (int i = 0; i < 4; ++i) {
        int r = i * 16 + r0;
        float4 v = *(const float4*)(we + (size_t)(hb + r) * HH + db + c4);
        tile[r][c4 + 0] = f2bf(v.x);
        tile[r][c4 + 1] = f2bf(v.y);
        tile[r][c4 + 2] = f2bf(v.z);
        tile[r][c4 + 3] = f2bf(v.w);
    }
    __syncthreads();
    unsigned short* wte = wt + (size_t)e * HH * HH;
    #pragma unroll
    for (int i = 0; i < 4; ++i) {
        int dr = i * 16 + r0;
        ushort4 o;
        o.x = tile[c4 + 0][dr];
        o.y = tile[c4 + 1][dr];
        o.z = tile[c4 + 2][dr];
        o.w = tile[c4 + 3][dr];
        *(ushort4*)(wte + (size_t)(db + dr) * HH + hb + c4) = o;
    }
}

// ---------------------------------------------------------------------------
// R1: router decide — gw in LDS; 512 threads, 8 waves x 2 tokens each
// (shorter serial chain, more resident waves). No atomics.
// ---------------------------------------------------------------------------
__global__ __launch_bounds__(512) void router_decide_kernel(
    const float* __restrict__ x, const float* __restrict__ gw,
    const float* __restrict__ gb, const float* __restrict__ eb,
    float* __restrict__ out, float* __restrict__ logits,
    unsigned short* __restrict__ xb, int* __restrict__ tops_i,
    float* __restrict__ tops_w)
{
    __shared__ float gwt[EE][HH];   // 32 KB: gwt[e][h] = gw[h][e]
    int tid = threadIdx.x;
    for (int i = tid; i < (HH * EE) / 4; i += 512) {
        float4 v = ((const float4*)gw)[i];
        int b4 = i * 4;
        gwt[(b4 + 0) & 7][(b4 + 0) >> 3] = v.x;
        gwt[(b4 + 1) & 7][(b4 + 1) >> 3] = v.y;
        gwt[(b4 + 2) & 7][(b4 + 2) >> 3] = v.z;
        gwt[(b4 + 3) & 7][(b4 + 3) >> 3] = v.w;
    }
    __syncthreads();

    const int lane = tid & 63;
    const int wv   = tid >> 6;

    #pragma unroll
    for (int tk = 0; tk < 2; ++tk) {
        const int t = blockIdx.x * 16 + wv * 2 + tk;
        const float* xrow = x + (size_t)t * HH;
        unsigned short* xbrow = xb + (size_t)t * HH;

        float acc[8];
        #pragma unroll
        for (int e = 0; e < 8; ++e) acc[e] = 0.0f;

        #pragma unroll
        for (int i = 0; i < 4; ++i) {
            int idx = i * 256 + lane * 4;
            float4 v = *(const float4*)(xrow + idx);
            ushort4 bv;
            bv.x = f2bf(v.x); bv.y = f2bf(v.y); bv.z = f2bf(v.z); bv.w = f2bf(v.w);
            *(ushort4*)(xbrow + idx) = bv;
            #pragma unroll
            for (int e = 0; e < 8; ++e) {
                float4 g = *(const float4*)(&gwt[e][idx]);
                acc[e] += v.x * g.x + v.y * g.y + v.z * g.z + v.w * g.w;
            }
        }
        #pragma unroll
        for (int e = 0; e < 8; ++e) {
            #pragma unroll
            for (int off = 32; off >= 1; off >>= 1)
                acc[e] += __shfl_xor(acc[e], off, 64);
        }
        float lg[8];
        #pragma unroll
        for (int e = 0; e < 8; ++e) lg[e] = acc[e] + gb[e];

        float myv = 0.0f;
        #pragma unroll
        for (int e = 0; e < 8; ++e) myv = (lane == e) ? lg[e] : myv;
        if (lane < 8) logits[(size_t)t * EE + lane] = myv;

        // top-2, lowest-index tie-break (matches lax.top_k; softmax monotone)
        int i0 = 0;
        #pragma unroll
        for (int e = 1; e < 8; ++e) if (lg[e] > lg[i0]) i0 = e;
        int i1 = (i0 == 0) ? 1 : 0;
        #pragma unroll
        for (int e = 0; e < 8; ++e) if (e != i0 && lg[e] > lg[i1]) i1 = e;

        float w0 = 1.0f / (1.0f + expf(lg[i1] - lg[i0])); // = p0/(p0+p1)
        float w1 = 1.0f - w0;

        if (lane == 0) {
            tops_i[t] = i0 | (i1 << 3);
            tops_w[t] = w0;
        }

        // out init = w0*b[i0] + w1*b[i1] (covers 0xAA poison)
        const float* b0 = eb + (size_t)i0 * HH;
        const float* b1 = eb + (size_t)i1 * HH;
        float* orow = out + (size_t)t * HH;
        #pragma unroll
        for (int i = 0; i < 4; ++i) {
            int idx = i * 256 + lane * 4;
            float4 a = *(const float4*)(b0 + idx);
            float4 c = *(const float4*)(b1 + idx);
            float4 r;
            r.x = w0 * a.x + w1 * c.x;
            r.y = w0 * a.y + w1 * c.y;
            r.z = w0 * a.z + w1 * c.z;
            r.w = w0 * a.w + w1 * c.w;
            *(float4*)(orow + idx) = r;
        }
    }
}

// ---------------------------------------------------------------------------
// R2: build gather lists hierarchically (LDS histogram, 8 global atomics
// per block of 256 tokens).
// ---------------------------------------------------------------------------
__global__ __launch_bounds__(256) void build_lists_kernel(
    const int* __restrict__ tops_i, const float* __restrict__ tops_w,
    int* __restrict__ counts, int* __restrict__ tokl, float* __restrict__ wl)
{
    __shared__ int lcnt[EE];
    __shared__ int gbase[EE];
    int tid = threadIdx.x;
    if (tid < EE) lcnt[tid] = 0;
    __syncthreads();

    int t   = blockIdx.x * 256 + tid;
    int rec = tops_i[t];
    int i0  = rec & 7;
    int i1  = (rec >> 3) & 7;
    float w0 = tops_w[t];
    float w1 = 1.0f - w0;

    int r0 = atomicAdd(&lcnt[i0], 1);
    int r1 = atomicAdd(&lcnt[i1], 1);
    __syncthreads();

    if (tid < EE) gbase[tid] = atomicAdd(&counts[tid], lcnt[tid]);
    __syncthreads();

    int p0 = gbase[i0] + r0;
    tokl[i0 * TT + p0] = t; wl[i0 * TT + p0] = w0;
    int p1 = gbase[i1] + r1;
    tokl[i1 * TT + p1] = t; wl[i1 * TT + p1] = w1;
}

// ---------------------------------------------------------------------------
// Grouped gathered GEMM with T3-minimum prefetch double-buffer:
// STAGE(next) issued BEFORE compute(current); one barrier per K-step keeps
// next-tile loads in flight under ds_read+MFMA. 128x128 tile, BK=64,
// 4 waves, 16x16x32 bf16 MFMA, atomicAdd epilogue. XCD-pinned experts (T1).
// ---------------------------------------------------------------------------
#define BM 128
#define BN 128
#define BK 64

__global__ __launch_bounds__(256) void moe_gemm_kernel(
    const unsigned short* __restrict__ xb, const unsigned short* __restrict__ wt,
    const int* __restrict__ counts, const int* __restrict__ tokl,
    const float* __restrict__ wl, float* __restrict__ out)
{
    int bid = blockIdx.x;
    int e   = bid & 7;            // expert == XCD (grid % 8 == 0)
    int j   = bid >> 3;
    int mb  = j >> 3;
    int nb  = j & 7;
    int cnt = counts[e];
    int row0 = mb * BM;
    if (row0 >= cnt) return;

    __shared__ __align__(16) unsigned short Alds[2][BM * BK];
    __shared__ __align__(16) unsigned short Blds[2][BN * BK];
    __shared__ int   toks[BM];
    __shared__ float wgts[BM];

    int tid = threadIdx.x;
    if (tid < BM) {
        int g = row0 + tid;
        bool ok = g < cnt;
        toks[tid] = ok ? tokl[e * TT + g] : 0;
        wgts[tid] = ok ? wl[e * TT + g] : 0.0f;
    }
    __syncthreads();

    const int lane = tid & 63;
    const int wv   = tid >> 6;
    const int wr   = wv >> 1, wc = wv & 1;
    const int mrow = wr * 64, ncol = wc * 64;

    f32x4 acc[4][4];
    #pragma unroll
    for (int m = 0; m < 4; ++m)
        #pragma unroll
        for (int n = 0; n < 4; ++n) acc[m][n] = (f32x4)0.0f;

    const unsigned short* wte = wt + (size_t)e * HH * HH + (size_t)(nb * BN) * HH;
    const int off = wv * 1024 + lane * 16;

    // hoist per-round gather bases (k0-invariant)
    const unsigned short* abase[4];
    const unsigned short* bbase[4];
    #pragma unroll
    for (int rnd = 0; rnd < 4; ++rnd) {
        int o  = rnd * 4096 + off;
        int r  = o >> 7;          // tile row (128 B per row)
        int cb = (o & 127) >> 1;  // element offset within row
        abase[rnd] = xb + (size_t)toks[r] * HH + cb;
        bbase[rnd] = wte + (size_t)r * HH + cb;
    }

#define STAGE(buf, k0)                                                         \
    {                                                                          \
        _Pragma("unroll")                                                      \
        for (int rnd = 0; rnd < 4; ++rnd) {                                    \
            __builtin_amdgcn_global_load_lds(                                  \
                (const __attribute__((address_space(1))) void*)(abase[rnd] + (k0)), \
                (__attribute__((address_space(3))) void*)((char*)&Alds[buf][0] + rnd * 4096 + wv * 1024), \
                16, 0, 0);                                                     \
            __builtin_amdgcn_global_load_lds(                                  \
                (const __attribute__((address_space(1))) void*)(bbase[rnd] + (k0)), \
                (__attribute__((address_space(3))) void*)((char*)&Blds[buf][0] + rnd * 4096 + wv * 1024), \
                16, 0, 0);                                                     \
        }                                                                      \
    }

#define COMPUTE(buf)                                                           \
    {                                                                          \
        _Pragma("unroll")                                                      \
        for (int kk = 0; kk < 2; ++kk) {                                       \
            int kb = kk * 64 + (lane >> 4) * 16;                               \
            short8 av[4], bv[4];                                               \
            _Pragma("unroll")                                                  \
            for (int m = 0; m < 4; ++m)                                        \
                av[m] = *(const short8*)((const char*)&Alds[buf][0] + (mrow + m * 16 + (lane & 15)) * 128 + kb); \
            _Pragma("unroll")                                                  \
            for (int n = 0; n < 4; ++n)                                        \
                bv[n] = *(const short8*)((const char*)&Blds[buf][0] + (ncol + n * 16 + (lane & 15)) * 128 + kb); \
            _Pragma("unroll")                                                  \
            for (int m = 0; m < 4; ++m)                                        \
                _Pragma("unroll")                                              \
                for (int n = 0; n < 4; ++n)                                    \
                    acc[m][n] = __builtin_amdgcn_mfma_f32_16x16x32_bf16(av[m], bv[n], acc[m][n], 0, 0, 0); \
        }                                                                      \
    }

    // prologue
    STAGE(0, 0);
    __syncthreads();

    // main loop: 16 K-steps, unrolled x2 for static buffer indices
    for (int kt = 0; kt < 14; kt += 2) {
        STAGE(1, (kt + 1) * BK);
        COMPUTE(0);
        __syncthreads();          // drains prefetch into buf1, protects buf0
        STAGE(0, (kt + 2) * BK);
        COMPUTE(1);
        __syncthreads();
    }
    // tail: kt = 14, 15
    STAGE(1, 15 * BK);
    COMPUTE(0);
    __syncthreads();
    COMPUTE(1);

#undef STAGE
#undef COMPUTE

    // epilogue: C/D mapping col=lane&15, row=(lane>>4)*4+reg
    #pragma unroll
    for (int m = 0; m < 4; ++m) {
        int lr0 = mrow + m * 16 + ((lane >> 4) << 2);
        #pragma unroll
        for (int rg = 0; rg < 4; ++rg) {
            int lr = lr0 + rg;
            int tkn = toks[lr];
            float wg = wgts[lr];
            if (wg != 0.0f) {
                float* orow = out + (size_t)tkn * HH + nb * BN + ncol + (lane & 15);
                #pragma unroll
                for (int n = 0; n < 4; ++n)
                    atomicAdd(orow + n * 16, wg * acc[m][n][rg]);
            }
        }
    }
}

// ---------------------------------------------------------------------------
extern "C" void kernel_launch(void* const* d_in, const int* in_sizes, int n_in,
                              void* d_out, int out_size, void* d_ws, size_t ws_size,
                              hipStream_t stream) {
    const float* x  = (const float*)d_in[0];
    const float* gw = (const float*)d_in[1];
    const float* gb = (const float*)d_in[2];
    const float* ew = (const float*)d_in[3];
    const float* eb = (const float*)d_in[4];
    float* out    = (float*)d_out;
    float* logits = out + (size_t)TT * HH;

    char* w = (char*)d_ws;
    unsigned short* xb = (unsigned short*)w;                                   // 32 MB
    unsigned short* wt = (unsigned short*)(w + (size_t)TT * HH * 2);           // 16 MB
    char* p  = w + (size_t)TT * HH * 2 + (size_t)EE * HH * HH * 2;
    int*   counts = (int*)p;                                                   // 32 B (+pad)
    int*   tokl   = (int*)(p + 256);                                           // 512 KB
    float* wl     = (float*)(p + 256 + (size_t)EE * TT * 4);                   // 512 KB
    int*   tops_i = (int*)(p + 256 + 2 * (size_t)EE * TT * 4);                 // 64 KB
    float* tops_w = (float*)(p + 256 + 2 * (size_t)EE * TT * 4 + TT * 4);      // 64 KB

    hipMemsetAsync(counts, 0, 256, stream);
    hipLaunchKernelGGL(transpose_w_kernel, dim3(EE * 256), dim3(256), 0, stream, ew, wt);
    hipLaunchKernelGGL(router_decide_kernel, dim3(TT / 16), dim3(512), 0, stream,
                       x, gw, gb, eb, out, logits, xb, tops_i, tops_w);
    hipLaunchKernelGGL(build_lists_kernel, dim3(TT / 256), dim3(256), 0, stream,
                       tops_i, tops_w, counts, tokl, wl);
    hipLaunchKernelGGL(moe_gemm_kernel, dim3(EE * (TT / BM) * (HH / BN)), dim3(256), 0, stream,
                       xb, wt, counts, tokl, wl, out);
}